// Round 1
// baseline (103.983 us; speedup 1.0000x reference)
//
#include <hip/hip_runtime.h>

// Problem constants
#define B_   2
#define H_   16
#define L_   2048
#define D_   64
#define BLK_ 32
#define NB_  64

// Structural: 4 query blocks per WG (8 waves / 512 threads), shared 11-tile window.
// Tile-staging traffic drops 39% vs the 2-block/WG version (9216 -> 5632 tile loads)
// at equal occupancy (2 WG/CU x 8 waves = 16 waves/CU).
#define WGQ  4
#define WIN  11                       // WINDOW + WGQ - 1
#define NWG  (B_ * H_ * (NB_ / WGQ)) // 512

// LDS strides (bf16 elements)
#define KSW 64   // K: unpadded, XOR-octet swizzle (oct ^ (row&7)) -> <=2-way conflicts
#define VS  40   // V^T: padded stride + XOR over 4 k-octets
#define PS  40   // per-wave P scratch

typedef __bf16 bf16x8 __attribute__((ext_vector_type(8)));
typedef __bf16 bf16x4 __attribute__((ext_vector_type(4)));
typedef float  f32x4  __attribute__((ext_vector_type(4)));

// log2(e) and 0.125*log2(e): softmax done in base-2 (v_exp_f32 IS exp2) ->
// one v_fma + one v_exp per element instead of fma+mul+exp.
#define LOG2E   1.44269504088896340736f
#define SC_LOG2 0.18033688011112042592f

// Barrier WITHOUT vmcnt drain: LDS ordering only. Global prefetch loads stay in
// flight across the barrier (they only feed this wave's own VGPRs).
#define WG_BARRIER() asm volatile("s_waitcnt lgkmcnt(0)\n\ts_barrier" ::: "memory")

struct Tile {
    float4 k0;       // this thread's K quarter-octet (row = tid>>4, f4 = tid&15)
    float  v[4];     // V^T gather: keys wave*4..+3 at d = lane
    float  kp0, kp1; // key_padding_mask cols l15, 16+l15 (pre-scaled by log2 e)
};

__global__ __launch_bounds__(512, 4)
void sparse_attn_kernel(const float* __restrict__ qg,
                        const float* __restrict__ kg,
                        const float* __restrict__ vg,
                        const float* __restrict__ kpm,
                        const int*   __restrict__ layout,
                        float* __restrict__ outg)
{
    __shared__ __align__(16) __bf16 Ks_[2][BLK_ * KSW];
    __shared__ __align__(16) __bf16 Vt_[2][D_ * VS];
    __shared__ __align__(16) __bf16 Ps_[8][16 * PS];

    const int tid  = threadIdx.x;
    const int wave = tid >> 6;
    const int lane = tid & 63;
    const int quad = lane >> 4;
    const int l15  = lane & 15;

    // XCD swizzle: 512 WGs over 8 XCDs; 64 consecutive logical WGs (overlapping
    // K/V windows, 4 full (b,h) ip-groups = 4 MB K+V) pinned to one XCD's L2.
    const int phys = blockIdx.x;
    const int lw   = (phys & 7) * 64 + (phys >> 3);
    const int ip = lw & 15;
    const int h  = (lw >> 4) & 15;
    const int b  = lw >> 8;
    const int i0 = ip * WGQ;
    const int iq = i0 + (wave >> 1);   // this wave's query block

    const size_t bh = (size_t)(b * H_ + h);
    const float* kbase  = kg  + bh * L_ * D_;
    const float* vbase  = vg  + bh * L_ * D_;
    const float* kpb    = kpm + (size_t)b * L_;
    const int*   layrow = layout + (h * NB_ + iq) * NB_;

    const int jbeg = i0 - 7;   // constant 11-slot window [i0-7, i0+3]

    // active bitmask up front (loads issued early; 1 VGPR instead of 11)
    unsigned int actmask = 0;
    #pragma unroll
    for (int s = 0; s < WIN; ++s) {
        const int j = jbeg + s;
        if (j >= 0 && layrow[j]) actmask |= (1u << s);
    }

    // ---- Q fragments: registers only ----
    bf16x8 aq[2];
    {
        const int gq = iq * BLK_ + (wave & 1) * 16 + l15;
        const float* qrow = qg + (bh * L_ + gq) * D_;
        #pragma unroll
        for (int ks = 0; ks < 2; ++ks) {
            float4 x = *(const float4*)&qrow[ks * 32 + quad * 8];
            float4 y = *(const float4*)&qrow[ks * 32 + quad * 8 + 4];
            bf16x8 pk;
            pk[0]=(__bf16)x.x; pk[1]=(__bf16)x.y; pk[2]=(__bf16)x.z; pk[3]=(__bf16)x.w;
            pk[4]=(__bf16)y.x; pk[5]=(__bf16)y.y; pk[6]=(__bf16)y.z; pk[7]=(__bf16)y.w;
            aq[ks] = pk;
        }
    }

    auto clampj = [&](int j) { return j < 0 ? 0 : j; };

    auto loadT = [&](int jc, Tile& T) {
        const float4* kb = (const float4*)(kbase + (size_t)jc * BLK_ * D_);
        T.k0 = kb[tid];                                  // 512 thr x 16B = full 8KB tile
        const float* vb = vbase + (size_t)jc * BLK_ * D_;
        #pragma unroll
        for (int i = 0; i < 4; ++i) T.v[i] = vb[(wave * 4 + i) * D_ + lane];
        T.kp0 = kpb[jc * BLK_ + l15]      * LOG2E;
        T.kp1 = kpb[jc * BLK_ + 16 + l15] * LOG2E;
    };

    auto storeT = [&](int buf, const Tile& T) {
        // K: thread covers row = tid>>4, d = (tid&15)*4 .. +3
        const int row = tid >> 4, f4 = tid & 15;
        const int oct = f4 >> 1, khalf = f4 & 1;
        bf16x4 pk;
        pk[0]=(__bf16)T.k0.x; pk[1]=(__bf16)T.k0.y; pk[2]=(__bf16)T.k0.z; pk[3]=(__bf16)T.k0.w;
        *(bf16x4*)&Ks_[buf][row * KSW + ((oct ^ (row & 7)) * 8) + khalf * 4] = pk;
        // V^T: keys wave*4..+3 at d = lane -> key-octet g = wave>>1, half = wave&1
        bf16x4 pv;
        #pragma unroll
        for (int i = 0; i < 4; ++i) pv[i] = (__bf16)T.v[i];
        const int g = wave >> 1, vhalf = wave & 1;
        *(bf16x4*)&Vt_[buf][lane * VS + ((g ^ (lane & 3)) * 8) + vhalf * 4] = pv;
    };

    // accumulators: no-max softmax (scores bounded; exp fp32-safe), deferred norm
    float lrow[4] = {0.f, 0.f, 0.f, 0.f};
    f32x4 Ot[4];
    #pragma unroll
    for (int t = 0; t < 4; ++t) Ot[t] = (f32x4){0.f, 0.f, 0.f, 0.f};

    auto computeT = [&](int buf, float kp0c, float kp1c) {
        f32x4 s0 = {0.f,0.f,0.f,0.f}, s1 = {0.f,0.f,0.f,0.f};
        #pragma unroll
        for (int ks = 0; ks < 2; ++ks) {
            const int so = ((ks * 4 + quad) ^ (l15 & 7)) * 8;
            bf16x8 b0 = *(const bf16x8*)&Ks_[buf][l15 * KSW + so];
            bf16x8 b1 = *(const bf16x8*)&Ks_[buf][(16 + l15) * KSW + so];
            s0 = __builtin_amdgcn_mfma_f32_16x16x32_bf16(aq[ks], b0, s0, 0, 0, 0);
            s1 = __builtin_amdgcn_mfma_f32_16x16x32_bf16(aq[ks], b1, s1, 0, 0, 0);
        }
        __bf16* psw = &Ps_[wave][0];
        #pragma unroll
        for (int r = 0; r < 4; ++r) {
            float p0 = exp2f(fmaf(s0[r], SC_LOG2, kp0c));
            float p1 = exp2f(fmaf(s1[r], SC_LOG2, kp1c));
            lrow[r] += p0 + p1;
            const int prow = quad * 4 + r;   // C-layout row
            psw[prow * PS + l15]      = (__bf16)p0;
            psw[prow * PS + 16 + l15] = (__bf16)p1;
        }
        // wave-internal LDS drain only (prefetch vmcnt stays in flight)
        asm volatile("s_waitcnt lgkmcnt(0)" ::: "memory");
        bf16x8 ap = *(const bf16x8*)&psw[l15 * PS + quad * 8];
        #pragma unroll
        for (int t = 0; t < 4; ++t) {
            bf16x8 bv = *(const bf16x8*)&Vt_[buf][(t * 16 + l15) * VS + ((quad ^ (l15 & 3)) * 8)];
            Ot[t] = __builtin_amdgcn_mfma_f32_16x16x32_bf16(ap, bv, Ot[t], 0, 0, 0);
        }
    };

    // ---- prologue: tile(jbeg) -> LDS buf0; tile(jbeg+1) -> regs ----
    Tile tiles[2];
    loadT(clampj(jbeg), tiles[0]);
    storeT(0, tiles[0]);
    float kp0c = tiles[0].kp0, kp1c = tiles[0].kp1;
    loadT(clampj(jbeg + 1), tiles[1]);   // consumed at s=0's store (parity (0+1)&1=1)
    WG_BARRIER();

    // ---- steady state: load(j+2) || compute(j) || store(j+1), one barrier/iter ----
    int cur = 0;
    #pragma unroll
    for (int s = 0; s < WIN; ++s) {
        const int j = jbeg + s;
        if (s <= WIN - 3) loadT(clampj(j + 2), tiles[s & 1]);   // distance-2 prefetch
        if (actmask & (1u << s)) computeT(cur, kp0c, kp1c);
        if (s < WIN - 1) {
            const Tile& T = tiles[(s + 1) & 1];                 // loaded at s-1 (or prologue)
            storeT(cur ^ 1, T);                                 // vmcnt(N) here, not 0
            kp0c = T.kp0; kp1c = T.kp1;
        }
        WG_BARRIER();
        cur ^= 1;
    }

    // ---- epilogue: reduce l over 16-lane row groups, normalize, store fp32 ----
    #pragma unroll
    for (int r = 0; r < 4; ++r) {
        #pragma unroll
        for (int m = 1; m < 16; m <<= 1) lrow[r] += __shfl_xor(lrow[r], m);
    }
    float* ob = outg + (bh * L_ + (size_t)iq * BLK_ + (wave & 1) * 16) * D_;
    #pragma unroll
    for (int r = 0; r < 4; ++r) {
        float inv = 1.0f / lrow[r];
        int prow = quad * 4 + r;
        #pragma unroll
        for (int t = 0; t < 4; ++t)
            ob[prow * D_ + t * 16 + l15] = Ot[t][r] * inv;
    }
}

extern "C" void kernel_launch(void* const* d_in, const int* in_sizes, int n_in,
                              void* d_out, int out_size, void* d_ws, size_t ws_size,
                              hipStream_t stream) {
    const float* q      = (const float*)d_in[0];
    const float* k      = (const float*)d_in[1];
    const float* v      = (const float*)d_in[2];
    const float* kpmask = (const float*)d_in[3];
    const int*   layout = (const int*)d_in[4];
    float* out = (float*)d_out;

    dim3 grid(NWG);     // 512 WGs; 8 waves; 4 query blocks per WG, 16 q-rows per wave
    dim3 block(512);
    sparse_attn_kernel<<<grid, block, 0, stream>>>(q, k, v, kpmask, layout, out);
}